// Round 4
// baseline (284.163 us; speedup 1.0000x reference)
//
#include <hip/hip_runtime.h>
#include <math.h>

#define B_  16
#define T_  4096
#define C_  64
#define KE_ 1023
#define BT_ (B_ * T_)

#define QBLK   256      // query-groups of 256 queries
#define KSPLIT 4        // code splits of 256 codes
#define KS_    256
#define TILE   64       // codes per LDS tile (16 KB)

// ---------------- ws layout (bytes) ----------------
// [64,      4160)    float ee[1024]       (|e_k|^2, ee[1023]=+inf pad)
// [4224,    528512)  u64   packed[BT]     (order(dist)<<32 | idx)
// [528512,  790656)  int   idxv[BT]
// [790656,  1052800) int   selpos[BT]
// [1052800, 1052864) int   nst[B]
// [1052864, 1053888) int   done[256]
// [1053888, 1054912) float commit_part[256]
// [1054912, 1055936) float valid_part[256]
// [1055936, 1057024) float smooth_part[272]  (256 in-block + 16 boundary)

__device__ __forceinline__ unsigned long long packkey(float d, int k) {
    unsigned int u = __float_as_uint(d);
    u = (u & 0x80000000u) ? ~u : (u | 0x80000000u);   // monotone total order
    return ((unsigned long long)u << 32) | (unsigned int)k;
}

// ---- init: packed = max-key, done = 0, ee = |e_k|^2 (+inf pad) ----
__global__ __launch_bounds__(256) void k_init(const float* __restrict__ cb,
                                              float* __restrict__ ee,
                                              unsigned long long* __restrict__ packed,
                                              int* __restrict__ done) {
    const int g = blockIdx.x * 256 + threadIdx.x;
    if (blockIdx.x < 256) { packed[g] = ~0ull; return; }
    const int r = g - BT_;                 // 0..1023
    if (r < 256) done[r] = 0;
    if (r < KE_) {
        const float* row = cb + (size_t)(r + 1) * C_;
        float s = 0.f;
        #pragma unroll
        for (int c = 0; c < C_; ++c) s = fmaf(row[c], row[c], s);
        ee[r] = s;
    } else if (r == KE_) {
        ee[r] = INFINITY;                  // pad code never wins
    }
}

// ---- hot kernel: lane-pair c-split, 4-way K-split, fused epilogue ----
// 1024 blocks (qb 0..255 x ks 0..3), 4 blocks/CU. Lane pair (2p,2p+1)
// jointly handles queries qa=Q0+2p, qa+1: each lane holds its 32-dim half
// of both rows (64 VGPR). Half-dots combined via shfl_xor(1); even lane
// tracks qa's argmin, odd lane tracks qa+1's -> lane tid tracks Q0+tid.
// Last-arrival block per qb (device-scope counter) runs the epilogue.
__global__ __launch_bounds__(256, 4) void k_assign(
    const float* __restrict__ z, const float* __restrict__ cb,
    const float* __restrict__ mask, const float* __restrict__ ee,
    unsigned long long* __restrict__ packed, int* __restrict__ done,
    float* __restrict__ zqo, int* __restrict__ idxv,
    float* __restrict__ commit_part, float* __restrict__ valid_part,
    float* __restrict__ smooth_part) {

    __shared__ float s_e[TILE * C_];       // 16 KB code tile
    __shared__ float s_ee[TILE];
    __shared__ int   s_last;
    __shared__ float s_red[12];

    const int tid  = threadIdx.x;
    const int lane = tid & 63;
    const int wave = tid >> 6;
    const int qb   = blockIdx.x & (QBLK - 1);
    const int ks   = blockIdx.x >> 8;
    const int Q0   = qb * 256;
    const int half = tid & 1;              // 0: c[0,32), 1: c[32,64)
    const int qmy  = Q0 + tid;             // query this lane tracks/finalizes
    const int qa   = Q0 + (tid & ~1);

    const float4* cb4 = (const float4*)cb;

    // load my 32-dim half of both pair queries; combine |z|^2 via shfl_xor
    float4 zA[8], zB[8];
    {
        const float4* pA = (const float4*)(z + (size_t)qa * C_) + half * 8;
        const float4* pB = (const float4*)(z + (size_t)(qa + 1) * C_) + half * 8;
        float sA = 0.f, sB = 0.f;
        #pragma unroll
        for (int i = 0; i < 8; ++i) {
            float4 a = pA[i], b = pB[i];
            zA[i] = a; zB[i] = b;
            sA = fmaf(a.x, a.x, sA); sA = fmaf(a.y, a.y, sA);
            sA = fmaf(a.z, a.z, sA); sA = fmaf(a.w, a.w, sA);
            sB = fmaf(b.x, b.x, sB); sB = fmaf(b.y, b.y, sB);
            sB = fmaf(b.z, b.z, sB); sB = fmaf(b.w, b.w, sB);
        }
        sA += __shfl_xor(sA, 1);
        sB += __shfl_xor(sB, 1);
        const float nA = fmaxf(sqrtf(sA), 1e-12f);
        const float nB = fmaxf(sqrtf(sB), 1e-12f);
        #pragma unroll
        for (int i = 0; i < 8; ++i) {
            zA[i].x /= nA; zA[i].y /= nA; zA[i].z /= nA; zA[i].w /= nA;
            zB[i].x /= nB; zB[i].y /= nB; zB[i].z /= nB; zB[i].w /= nB;
        }
    }

    float best = INFINITY;
    int   bk   = 0;

    for (int tile = 0; tile < KS_ / TILE; ++tile) {
        const int tbase = ks * KS_ + tile * TILE;
        __syncthreads();
        #pragma unroll
        for (int j = 0; j < 4; ++j) {      // 1024 float4 / 256 threads
            int f    = j * 256 + tid;
            int row  = f >> 4;
            int k    = tbase + row;
            int crow = (k + 1 <= KE_) ? (k + 1) : KE_;
            ((float4*)s_e)[f] = cb4[crow * 16 + (f & 15)];
        }
        if (tid < TILE) s_ee[tid] = ee[tbase + tid];
        __syncthreads();

        #pragma unroll 1
        for (int kk = 0; kk < TILE; kk += 4) {
            const float4* r0 = (const float4*)(s_e + (kk + 0) * C_) + half * 8;
            const float4* r1 = (const float4*)(s_e + (kk + 1) * C_) + half * 8;
            const float4* r2 = (const float4*)(s_e + (kk + 2) * C_) + half * 8;
            const float4* r3 = (const float4*)(s_e + (kk + 3) * C_) + half * 8;
            float hA0 = 0.f, hA1 = 0.f, hA2 = 0.f, hA3 = 0.f;
            float hB0 = 0.f, hB1 = 0.f, hB2 = 0.f, hB3 = 0.f;
            #pragma unroll
            for (int i = 0; i < 8; ++i) {
                const float4 a0 = r0[i], a1 = r1[i], a2 = r2[i], a3 = r3[i];
                const float4 x = zA[i], y = zB[i];
                hA0 = fmaf(x.x, a0.x, hA0); hA0 = fmaf(x.y, a0.y, hA0);
                hA0 = fmaf(x.z, a0.z, hA0); hA0 = fmaf(x.w, a0.w, hA0);
                hA1 = fmaf(x.x, a1.x, hA1); hA1 = fmaf(x.y, a1.y, hA1);
                hA1 = fmaf(x.z, a1.z, hA1); hA1 = fmaf(x.w, a1.w, hA1);
                hA2 = fmaf(x.x, a2.x, hA2); hA2 = fmaf(x.y, a2.y, hA2);
                hA2 = fmaf(x.z, a2.z, hA2); hA2 = fmaf(x.w, a2.w, hA2);
                hA3 = fmaf(x.x, a3.x, hA3); hA3 = fmaf(x.y, a3.y, hA3);
                hA3 = fmaf(x.z, a3.z, hA3); hA3 = fmaf(x.w, a3.w, hA3);
                hB0 = fmaf(y.x, a0.x, hB0); hB0 = fmaf(y.y, a0.y, hB0);
                hB0 = fmaf(y.z, a0.z, hB0); hB0 = fmaf(y.w, a0.w, hB0);
                hB1 = fmaf(y.x, a1.x, hB1); hB1 = fmaf(y.y, a1.y, hB1);
                hB1 = fmaf(y.z, a1.z, hB1); hB1 = fmaf(y.w, a1.w, hB1);
                hB2 = fmaf(y.x, a2.x, hB2); hB2 = fmaf(y.y, a2.y, hB2);
                hB2 = fmaf(y.z, a2.z, hB2); hB2 = fmaf(y.w, a2.w, hB2);
                hB3 = fmaf(y.x, a3.x, hB3); hB3 = fmaf(y.y, a3.y, hB3);
                hB3 = fmaf(y.z, a3.z, hB3); hB3 = fmaf(y.w, a3.w, hB3);
            }
            // exchange: I send my half of the PARTNER's tracked query,
            // receive the partner's half of MINE.
            const float s0 = half ? hA0 : hB0;
            const float s1 = half ? hA1 : hB1;
            const float s2 = half ? hA2 : hB2;
            const float s3 = half ? hA3 : hB3;
            const float f0 = (half ? hB0 : hA0) + __shfl_xor(s0, 1);
            const float f1 = (half ? hB1 : hA1) + __shfl_xor(s1, 1);
            const float f2 = (half ? hB2 : hA2) + __shfl_xor(s2, 1);
            const float f3 = (half ? hB3 : hA3) + __shfl_xor(s3, 1);
            const int kb = tbase + kk;
            float v;
            v = fmaf(-2.f, f0, s_ee[kk + 0]); if (v < best) { best = v; bk = kb + 0; }
            v = fmaf(-2.f, f1, s_ee[kk + 1]); if (v < best) { best = v; bk = kb + 1; }
            v = fmaf(-2.f, f2, s_ee[kk + 2]); if (v < best) { best = v; bk = kb + 2; }
            v = fmaf(-2.f, f3, s_ee[kk + 3]); if (v < best) { best = v; bk = kb + 3; }
        }
    }

    atomicMin(&packed[qmy], packkey(best, bk));
    __threadfence();
    __syncthreads();
    if (tid == 0) {
        int old = __hip_atomic_fetch_add(&done[qb], 1, __ATOMIC_ACQ_REL,
                                         __HIP_MEMORY_SCOPE_AGENT);
        s_last = (old == KSPLIT - 1);
    }
    __syncthreads();
    if (!s_last) return;

    // ---- fused epilogue: this block finalizes queries Q0..Q0+255 ----
    const unsigned long long pk =
        __hip_atomic_load(&packed[qmy], __ATOMIC_RELAXED, __HIP_MEMORY_SCOPE_AGENT);
    const int bi = (int)(unsigned int)(pk & 0xFFFFFFFFull);
    idxv[qmy] = bi;
    const float m     = mask[qmy];
    const float mnext = (tid < 255) ? mask[qmy + 1] : 0.f;  // pair (qmy,qmy+1)

    const float4* zp = (const float4*)(z + (size_t)qmy * C_);
    const float4* er = (const float4*)(cb + (size_t)(bi + 1) * C_);
    float4* zo = (float4*)(zqo + (size_t)qmy * C_);
    float4* s4 = (float4*)s_e;             // alias the tile buffer

    float4 zr[16];
    float ss = 0.f;
    #pragma unroll
    for (int i = 0; i < 16; ++i) {
        float4 v = zp[i];
        zr[i] = v;
        ss = fmaf(v.x, v.x, ss); ss = fmaf(v.y, v.y, ss);
        ss = fmaf(v.z, v.z, ss); ss = fmaf(v.w, v.w, ss);
    }
    const float nrm = fmaxf(sqrtf(ss), 1e-12f);

    float commit = 0.f, sm = 0.f;
    for (int c4 = 0; c4 < 16; ++c4) {
        const float z0 = zr[c4].x / nrm, z1 = zr[c4].y / nrm;
        const float z2 = zr[c4].z / nrm, z3 = zr[c4].w / nrm;
        const float4 e4 = er[c4];
        const float q0 = e4.x * m, q1 = e4.y * m, q2 = e4.z * m, q3 = e4.w * m;
        float4 o;
        o.x = (z0 + q0) - z0;              // straight-through forward value
        o.y = (z1 + q1) - z1;
        o.z = (z2 + q2) - z2;
        o.w = (z3 + q3) - z3;
        zo[c4] = o;
        const float d0 = z0 - q0, d1 = z1 - q1, d2 = z2 - q2, d3 = z3 - q3;
        commit = fmaf(d0, d0, commit); commit = fmaf(d1, d1, commit);
        commit = fmaf(d2, d2, commit); commit = fmaf(d3, d3, commit);
        // in-block smoothness pair (qmy, qmy+1) via LDS chunk
        s4[tid] = o;
        __syncthreads();
        if (tid < 255) {
            const float4 nb = s4[tid + 1];
            const float x0 = o.x - nb.x, x1 = o.y - nb.y;
            const float x2 = o.z - nb.z, x3 = o.w - nb.w;
            sm = fmaf(x0, x0, sm); sm = fmaf(x1, x1, sm);
            sm = fmaf(x2, x2, sm); sm = fmaf(x3, x3, sm);
        }
        __syncthreads();
    }
    commit *= m;
    sm     *= mnext;
    float vc = m;
    #pragma unroll
    for (int off = 32; off > 0; off >>= 1) {
        commit += __shfl_down(commit, off);
        vc     += __shfl_down(vc, off);
        sm     += __shfl_down(sm, off);
    }
    if (lane == 0) { s_red[wave] = commit; s_red[4 + wave] = vc; s_red[8 + wave] = sm; }
    __syncthreads();
    if (tid == 0) {
        commit_part[qb] = s_red[0] + s_red[1] + s_red[2] + s_red[3];
        valid_part[qb]  = s_red[4] + s_red[5] + s_red[6] + s_red[7];
        smooth_part[qb] = s_red[8] + s_red[9] + s_red[10] + s_red[11];
    }
}

// ---- per-batch start compaction + boundary smoothness pairs ----
__global__ __launch_bounds__(256) void k_scan(const int* __restrict__ idxv,
                                              const float* __restrict__ mask,
                                              const float* __restrict__ zqo,
                                              int* __restrict__ selpos,
                                              int* __restrict__ nst,
                                              float* __restrict__ smooth_part) {
    __shared__ int cnt[256];
    __shared__ float sred[4];
    const int b = blockIdx.x;
    const int tid = threadIdx.x;
    const int base = b * T_;
    const int t0 = tid * 16;

    int flags = 0, c = 0;
    int prev = (tid == 0) ? -1 : idxv[base + t0 - 1];
    #pragma unroll
    for (int i = 0; i < 16; ++i) {
        const int t = t0 + i;
        const int cur = idxv[base + t];
        const int is = (t == 0) ? 1
                     : ((cur != prev && mask[base + t] > 0.f) ? 1 : 0);
        flags |= is << i;
        c += is;
        prev = cur;
    }
    cnt[tid] = c;
    __syncthreads();
    for (int off = 1; off < 256; off <<= 1) {
        int add = (tid >= off) ? cnt[tid - off] : 0;
        __syncthreads();
        cnt[tid] += add;
        __syncthreads();
    }
    int pos = cnt[tid] - c;   // exclusive prefix
    #pragma unroll
    for (int i = 0; i < 16; ++i) {
        if ((flags >> i) & 1) selpos[base + pos++] = t0 + i;
    }
    if (tid == 255) nst[b] = cnt[255];

    // boundary smoothness pairs: (q-1, q) at q = base + j*256, j=1..15
    float v = 0.f;
    for (int e = tid; e < 15 * 64; e += 256) {
        const int j = e >> 6, cc = e & 63;
        const int q = base + (j + 1) * 256;
        const float d = zqo[(size_t)(q - 1) * C_ + cc] - zqo[(size_t)q * C_ + cc];
        v = fmaf(d * mask[q], d, v);
    }
    #pragma unroll
    for (int off = 32; off > 0; off >>= 1) v += __shfl_down(v, off);
    if ((tid & 63) == 0) sred[tid >> 6] = v;
    __syncthreads();
    if (tid == 0) smooth_part[256 + b] = sred[0] + sred[1] + sred[2] + sred[3];
}

// ---- fused n_z_q gather + n_mask + selected_encodings ----
__global__ __launch_bounds__(256) void k_gsel(const float* __restrict__ zqo,
                                              const int* __restrict__ idxv,
                                              const int* __restrict__ selpos,
                                              const int* __restrict__ nst,
                                              float* __restrict__ nzq,
                                              float* __restrict__ nmask,
                                              float* __restrict__ sel) {
    const int gid = blockIdx.x * 256 + threadIdx.x;   // float4 index
    const int b   = gid >> 16;          // T*C/4 = 65536 float4 per batch
    const int rem = gid & 65535;
    const int j   = rem >> 4;
    const int c4  = rem & 15;
    const int n   = nst[b];
    float4 v = make_float4(0.f, 0.f, 0.f, 0.f);
    int p = 0;
    if (j < n) {
        p = selpos[b * T_ + j];
        v = ((const float4*)zqo)[((size_t)b * T_ + p) * 16 + c4];
    }
    ((float4*)nzq)[gid] = v;
    if (c4 == 0) {
        float nm = 0.f, s = 0.f;
        if (j < n) { nm = 1.f; s = (float)(idxv[b * T_ + p] + 1); }
        nmask[b * T_ + j] = nm;
        sel[b * T_ + j]   = s;
    }
}

// ---- final reduction of partials -> losses ----
__global__ __launch_bounds__(256) void k_final(const float* __restrict__ commit_part,
                                               const float* __restrict__ valid_part,
                                               const float* __restrict__ smooth_part,
                                               float* __restrict__ out) {
    __shared__ double rc[256];
    __shared__ double rv[256];
    __shared__ double rs[256];
    const int tid = threadIdx.x;
    double sc = (double)commit_part[tid];
    double sv = (double)valid_part[tid];
    double ssm = (double)smooth_part[tid];
    if (tid < 16) ssm += (double)smooth_part[256 + tid];
    rc[tid] = sc; rv[tid] = sv; rs[tid] = ssm;
    __syncthreads();
    for (int off = 128; off > 0; off >>= 1) {
        if (tid < off) {
            rc[tid] += rc[tid + off];
            rv[tid] += rv[tid + off];
            rs[tid] += rs[tid + off];
        }
        __syncthreads();
    }
    if (tid == 0) {
        double valid = rv[0];
        out[0] = (float)(rs[0] / (valid - (double)B_));  // m1.sum() = valid - B
        out[1] = (float)(rc[0] / valid);
    }
}

extern "C" void kernel_launch(void* const* d_in, const int* in_sizes, int n_in,
                              void* d_out, int out_size, void* d_ws, size_t ws_size,
                              hipStream_t stream) {
    const float* z    = (const float*)d_in[0];
    const float* cb   = (const float*)d_in[1];
    const float* mask = (const float*)d_in[2];
    float* out = (float*)d_out;
    char* ws = (char*)d_ws;

    float*              ee          = (float*)(ws + 64);
    unsigned long long* packed      = (unsigned long long*)(ws + 4224);
    int*                idxv        = (int*)(ws + 528512);
    int*                selpos      = (int*)(ws + 790656);
    int*                nst         = (int*)(ws + 1052800);
    int*                done        = (int*)(ws + 1052864);
    float*              commit_part = (float*)(ws + 1053888);
    float*              valid_part  = (float*)(ws + 1054912);
    float*              smooth_part = (float*)(ws + 1055936);

    float* zqo   = out + 2;
    float* nzq   = zqo + (size_t)BT_ * C_;
    float* nmask = nzq + (size_t)BT_ * C_;
    float* sel   = nmask + BT_;

    k_init  <<<260,           256, 0, stream>>>(cb, ee, packed, done);
    k_assign<<<QBLK * KSPLIT, 256, 0, stream>>>(z, cb, mask, ee, packed, done,
                                                zqo, idxv, commit_part,
                                                valid_part, smooth_part);
    k_scan  <<<B_,            256, 0, stream>>>(idxv, mask, zqo, selpos, nst,
                                                smooth_part);
    k_gsel  <<<4096,          256, 0, stream>>>(zqo, idxv, selpos, nst,
                                                nzq, nmask, sel);
    k_final <<<1,             256, 0, stream>>>(commit_part, valid_part,
                                                smooth_part, out);
}

// Round 5
// 245.140 us; speedup vs baseline: 1.1592x; 1.1592x over previous
//
#include <hip/hip_runtime.h>
#include <math.h>

#define B_  16
#define T_  4096
#define C_  64
#define KE_ 1023
#define BT_ (B_ * T_)

#define QBLK   128      // query-groups of 512 queries (2/thread)
#define KSPLIT 8        // code splits of 128 codes
#define KS_    128
#define TILE   64       // codes per LDS tile (16 KB)

// ---------------- ws layout (bytes) ----------------
// [64,      4160)    float ee[1024]       (|e_k|^2, ee[1023]=+inf pad)
// [4224,    528512)  u64   packed[BT]     (order(dist)<<32 | idx)
// [528512,  790656)  int   idxv[BT]
// [790656,  1052800) int   selpos[BT]
// [1052800, 1052864) int   nst[B]
// [1053888, 1054912) float commit_part[256]
// [1054912, 1055936) float valid_part[256]
// [1055936, 1057024) float smooth_part[272]  (256 in-block + 16 boundary)

__device__ __forceinline__ unsigned long long packkey(float d, int k) {
    unsigned int u = __float_as_uint(d);
    u = (u & 0x80000000u) ? ~u : (u | 0x80000000u);   // monotone total order
    return ((unsigned long long)u << 32) | (unsigned int)k;
}

// ---- init: packed = max-key, ee = |e_k|^2 (+inf pad) ----
__global__ __launch_bounds__(256) void k_init(const float* __restrict__ cb,
                                              float* __restrict__ ee,
                                              unsigned long long* __restrict__ packed) {
    const int g = blockIdx.x * 256 + threadIdx.x;
    if (blockIdx.x < 256) { packed[g] = ~0ull; return; }
    const int r = g - BT_;                 // 0..1023
    if (r < KE_) {
        const float* row = cb + (size_t)(r + 1) * C_;
        float s = 0.f;
        #pragma unroll
        for (int c = 0; c < C_; ++c) s = fmaf(row[c], row[c], s);
        ee[r] = s;
    } else if (r == KE_) {
        ee[r] = INFINITY;                  // pad code never wins
    }
}

// ---- hot kernel: 2 queries/thread, 8-way K-split, LDS 64-code tiles ----
// grid = QBLK * KSPLIT = 1024 blocks (~3-4/CU). Each staged code row feeds
// 8 FMAs (2 queries x 4 floats) per ds_read_b128 -> VALU-bound (LDS ~75%).
// Result per (query, split): packed (orderdist<<32|k) via atomicMin.
__global__ __launch_bounds__(256, 2) void k_assign(
    const float* __restrict__ z, const float* __restrict__ cb,
    const float* __restrict__ ee, unsigned long long* __restrict__ packed) {

    __shared__ float s_e[TILE * C_];    // 16 KB
    __shared__ float s_ee[TILE];

    const int tid = threadIdx.x;
    const int qb  = blockIdx.x & (QBLK - 1);
    const int ks  = blockIdx.x >> 7;
    const int ksbase = ks * KS_;
    const int q0 = qb * 512 + tid;
    const int q1 = q0 + 256;

    // load + normalize both z rows into registers
    float4 zq0[16], zq1[16];
    {
        const float4* p0 = (const float4*)(z + (size_t)q0 * C_);
        const float4* p1 = (const float4*)(z + (size_t)q1 * C_);
        float s0 = 0.f, s1 = 0.f;
        #pragma unroll
        for (int i = 0; i < 16; ++i) {
            float4 a = p0[i], b = p1[i];
            zq0[i] = a; zq1[i] = b;
            s0 = fmaf(a.x, a.x, s0); s0 = fmaf(a.y, a.y, s0);
            s0 = fmaf(a.z, a.z, s0); s0 = fmaf(a.w, a.w, s0);
            s1 = fmaf(b.x, b.x, s1); s1 = fmaf(b.y, b.y, s1);
            s1 = fmaf(b.z, b.z, s1); s1 = fmaf(b.w, b.w, s1);
        }
        const float n0 = fmaxf(sqrtf(s0), 1e-12f);
        const float n1 = fmaxf(sqrtf(s1), 1e-12f);
        #pragma unroll
        for (int i = 0; i < 16; ++i) {
            zq0[i].x /= n0; zq0[i].y /= n0; zq0[i].z /= n0; zq0[i].w /= n0;
            zq1[i].x /= n1; zq1[i].y /= n1; zq1[i].z /= n1; zq1[i].w /= n1;
        }
    }

    float b0 = INFINITY, b1 = INFINITY;
    int   i0 = 0,        i1 = 0;

    for (int tile = 0; tile < KS_ / TILE; ++tile) {
        const int tbase = ksbase + tile * TILE;
        __syncthreads();
        // stage 64 code rows: 1024 float4, 4 per thread
        #pragma unroll
        for (int j = 0; j < 4; ++j) {
            int f    = j * 256 + tid;
            int row  = f >> 4;
            int k    = tbase + row;
            int crow = (k + 1 <= KE_) ? (k + 1) : KE_;   // clamp pad row
            ((float4*)s_e)[f] = ((const float4*)cb)[crow * 16 + (f & 15)];
        }
        if (tid < TILE) s_ee[tid] = ee[tbase + tid];     // inf at pad
        __syncthreads();

        #pragma unroll 1
        for (int kk = 0; kk < TILE; kk += 4) {
            const float4* r0 = (const float4*)(s_e + (kk + 0) * C_);
            const float4* r1 = (const float4*)(s_e + (kk + 1) * C_);
            const float4* r2 = (const float4*)(s_e + (kk + 2) * C_);
            const float4* r3 = (const float4*)(s_e + (kk + 3) * C_);
            float d00 = 0.f, d01 = 0.f, d02 = 0.f, d03 = 0.f;
            float d10 = 0.f, d11 = 0.f, d12 = 0.f, d13 = 0.f;
            #pragma unroll
            for (int c4 = 0; c4 < 16; ++c4) {
                const float4 a0 = r0[c4];
                const float4 a1 = r1[c4];
                const float4 a2 = r2[c4];
                const float4 a3 = r3[c4];
                const float4 x  = zq0[c4];
                const float4 y  = zq1[c4];
                d00 = fmaf(x.x, a0.x, d00); d00 = fmaf(x.y, a0.y, d00);
                d00 = fmaf(x.z, a0.z, d00); d00 = fmaf(x.w, a0.w, d00);
                d01 = fmaf(x.x, a1.x, d01); d01 = fmaf(x.y, a1.y, d01);
                d01 = fmaf(x.z, a1.z, d01); d01 = fmaf(x.w, a1.w, d01);
                d02 = fmaf(x.x, a2.x, d02); d02 = fmaf(x.y, a2.y, d02);
                d02 = fmaf(x.z, a2.z, d02); d02 = fmaf(x.w, a2.w, d02);
                d03 = fmaf(x.x, a3.x, d03); d03 = fmaf(x.y, a3.y, d03);
                d03 = fmaf(x.w, a3.w, d03); d03 = fmaf(x.z, a3.z, d03);
                d10 = fmaf(y.x, a0.x, d10); d10 = fmaf(y.y, a0.y, d10);
                d10 = fmaf(y.z, a0.z, d10); d10 = fmaf(y.w, a0.w, d10);
                d11 = fmaf(y.x, a1.x, d11); d11 = fmaf(y.y, a1.y, d11);
                d11 = fmaf(y.z, a1.z, d11); d11 = fmaf(y.w, a1.w, d11);
                d12 = fmaf(y.x, a2.x, d12); d12 = fmaf(y.y, a2.y, d12);
                d12 = fmaf(y.z, a2.z, d12); d12 = fmaf(y.w, a2.w, d12);
                d13 = fmaf(y.x, a3.x, d13); d13 = fmaf(y.y, a3.y, d13);
                d13 = fmaf(y.z, a3.z, d13); d13 = fmaf(y.w, a3.w, d13);
            }
            const int kb = tbase + kk;
            const float e0 = s_ee[kk + 0], e1 = s_ee[kk + 1];
            const float e2 = s_ee[kk + 2], e3 = s_ee[kk + 3];
            float v;
            v = fmaf(-2.f, d00, e0); if (v < b0) { b0 = v; i0 = kb + 0; }
            v = fmaf(-2.f, d01, e1); if (v < b0) { b0 = v; i0 = kb + 1; }
            v = fmaf(-2.f, d02, e2); if (v < b0) { b0 = v; i0 = kb + 2; }
            v = fmaf(-2.f, d03, e3); if (v < b0) { b0 = v; i0 = kb + 3; }
            v = fmaf(-2.f, d10, e0); if (v < b1) { b1 = v; i1 = kb + 0; }
            v = fmaf(-2.f, d11, e1); if (v < b1) { b1 = v; i1 = kb + 1; }
            v = fmaf(-2.f, d12, e2); if (v < b1) { b1 = v; i1 = kb + 2; }
            v = fmaf(-2.f, d13, e3); if (v < b1) { b1 = v; i1 = kb + 3; }
        }
    }

    atomicMin(&packed[q0], packkey(b0, i0));
    atomicMin(&packed[q1], packkey(b1, i1));
}

// ---- epilogue: idx, z_q, commit/valid partials + in-block smoothness ----
__global__ __launch_bounds__(256) void k_epi(
    const float* __restrict__ z, const float* __restrict__ cb,
    const float* __restrict__ mask, const unsigned long long* __restrict__ packed,
    float* __restrict__ zqo, int* __restrict__ idxv,
    float* __restrict__ commit_part, float* __restrict__ valid_part,
    float* __restrict__ smooth_part) {

    __shared__ float4 s4[256];
    __shared__ float s_red[12];
    const int tid  = threadIdx.x;
    const int lane = tid & 63;
    const int wave = tid >> 6;
    const int q    = blockIdx.x * 256 + tid;

    const int bi = (int)(unsigned int)(packed[q] & 0xFFFFFFFFull);
    idxv[q] = bi;
    const float m     = mask[q];
    const float mnext = (tid < 255) ? mask[q + 1] : 0.f;   // pair (q, q+1)

    const float4* zp = (const float4*)(z + (size_t)q * C_);
    const float4* er = (const float4*)(cb + (size_t)(bi + 1) * C_);
    float4* zo = (float4*)(zqo + (size_t)q * C_);

    float4 zr[16];
    float ss = 0.f;
    #pragma unroll
    for (int i = 0; i < 16; ++i) {
        float4 v = zp[i];
        zr[i] = v;
        ss = fmaf(v.x, v.x, ss); ss = fmaf(v.y, v.y, ss);
        ss = fmaf(v.z, v.z, ss); ss = fmaf(v.w, v.w, ss);
    }
    const float nrm = fmaxf(sqrtf(ss), 1e-12f);

    float commit = 0.f, sm = 0.f;
    for (int c4 = 0; c4 < 16; ++c4) {
        const float z0 = zr[c4].x / nrm, z1 = zr[c4].y / nrm;
        const float z2 = zr[c4].z / nrm, z3 = zr[c4].w / nrm;
        const float4 e4 = er[c4];
        const float q0 = e4.x * m, q1 = e4.y * m, q2 = e4.z * m, q3 = e4.w * m;
        float4 o;
        o.x = (z0 + q0) - z0;              // straight-through forward value
        o.y = (z1 + q1) - z1;
        o.z = (z2 + q2) - z2;
        o.w = (z3 + q3) - z3;
        zo[c4] = o;
        const float d0 = z0 - q0, d1 = z1 - q1, d2 = z2 - q2, d3 = z3 - q3;
        commit = fmaf(d0, d0, commit); commit = fmaf(d1, d1, commit);
        commit = fmaf(d2, d2, commit); commit = fmaf(d3, d3, commit);
        // in-block smoothness pair (q, q+1) via LDS chunk
        s4[tid] = o;
        __syncthreads();
        if (tid < 255) {
            const float4 nb = s4[tid + 1];
            const float x0 = o.x - nb.x, x1 = o.y - nb.y;
            const float x2 = o.z - nb.z, x3 = o.w - nb.w;
            sm = fmaf(x0, x0, sm); sm = fmaf(x1, x1, sm);
            sm = fmaf(x2, x2, sm); sm = fmaf(x3, x3, sm);
        }
        __syncthreads();
    }
    commit *= m;
    sm     *= mnext;
    float vc = m;
    #pragma unroll
    for (int off = 32; off > 0; off >>= 1) {
        commit += __shfl_down(commit, off);
        vc     += __shfl_down(vc, off);
        sm     += __shfl_down(sm, off);
    }
    if (lane == 0) { s_red[wave] = commit; s_red[4 + wave] = vc; s_red[8 + wave] = sm; }
    __syncthreads();
    if (tid == 0) {
        commit_part[blockIdx.x] = s_red[0] + s_red[1] + s_red[2] + s_red[3];
        valid_part[blockIdx.x]  = s_red[4] + s_red[5] + s_red[6] + s_red[7];
        smooth_part[blockIdx.x] = s_red[8] + s_red[9] + s_red[10] + s_red[11];
    }
}

// ---- per-batch start compaction + boundary smoothness pairs ----
__global__ __launch_bounds__(256) void k_scan(const int* __restrict__ idxv,
                                              const float* __restrict__ mask,
                                              const float* __restrict__ zqo,
                                              int* __restrict__ selpos,
                                              int* __restrict__ nst,
                                              float* __restrict__ smooth_part) {
    __shared__ int cnt[256];
    __shared__ float sred[4];
    const int b = blockIdx.x;
    const int tid = threadIdx.x;
    const int base = b * T_;
    const int t0 = tid * 16;

    int flags = 0, c = 0;
    int prev = (tid == 0) ? -1 : idxv[base + t0 - 1];
    #pragma unroll
    for (int i = 0; i < 16; ++i) {
        const int t = t0 + i;
        const int cur = idxv[base + t];
        const int is = (t == 0) ? 1
                     : ((cur != prev && mask[base + t] > 0.f) ? 1 : 0);
        flags |= is << i;
        c += is;
        prev = cur;
    }
    cnt[tid] = c;
    __syncthreads();
    for (int off = 1; off < 256; off <<= 1) {
        int add = (tid >= off) ? cnt[tid - off] : 0;
        __syncthreads();
        cnt[tid] += add;
        __syncthreads();
    }
    int pos = cnt[tid] - c;   // exclusive prefix
    #pragma unroll
    for (int i = 0; i < 16; ++i) {
        if ((flags >> i) & 1) selpos[base + pos++] = t0 + i;
    }
    if (tid == 255) nst[b] = cnt[255];

    // boundary smoothness pairs: (q-1, q) at q = base + j*256, j=1..15
    float v = 0.f;
    for (int e = tid; e < 15 * 64; e += 256) {
        const int j = e >> 6, cc = e & 63;
        const int q = base + (j + 1) * 256;
        const float d = zqo[(size_t)(q - 1) * C_ + cc] - zqo[(size_t)q * C_ + cc];
        v = fmaf(d * mask[q], d, v);
    }
    #pragma unroll
    for (int off = 32; off > 0; off >>= 1) v += __shfl_down(v, off);
    if ((tid & 63) == 0) sred[tid >> 6] = v;
    __syncthreads();
    if (tid == 0) smooth_part[256 + b] = sred[0] + sred[1] + sred[2] + sred[3];
}

// ---- fused n_z_q gather + n_mask + selected_encodings ----
__global__ __launch_bounds__(256) void k_gsel(const float* __restrict__ zqo,
                                              const int* __restrict__ idxv,
                                              const int* __restrict__ selpos,
                                              const int* __restrict__ nst,
                                              float* __restrict__ nzq,
                                              float* __restrict__ nmask,
                                              float* __restrict__ sel) {
    const int gid = blockIdx.x * 256 + threadIdx.x;   // float4 index
    const int b   = gid >> 16;          // T*C/4 = 65536 float4 per batch
    const int rem = gid & 65535;
    const int j   = rem >> 4;
    const int c4  = rem & 15;
    const int n   = nst[b];
    float4 v = make_float4(0.f, 0.f, 0.f, 0.f);
    int p = 0;
    if (j < n) {
        p = selpos[b * T_ + j];
        v = ((const float4*)zqo)[((size_t)b * T_ + p) * 16 + c4];
    }
    ((float4*)nzq)[gid] = v;
    if (c4 == 0) {
        float nm = 0.f, s = 0.f;
        if (j < n) { nm = 1.f; s = (float)(idxv[b * T_ + p] + 1); }
        nmask[b * T_ + j] = nm;
        sel[b * T_ + j]   = s;
    }
}

// ---- final reduction of partials -> losses ----
__global__ __launch_bounds__(256) void k_final(const float* __restrict__ commit_part,
                                               const float* __restrict__ valid_part,
                                               const float* __restrict__ smooth_part,
                                               float* __restrict__ out) {
    __shared__ double rc[256];
    __shared__ double rv[256];
    __shared__ double rs[256];
    const int tid = threadIdx.x;
    double sc = (double)commit_part[tid];
    double sv = (double)valid_part[tid];
    double ssm = (double)smooth_part[tid];
    if (tid < 16) ssm += (double)smooth_part[256 + tid];
    rc[tid] = sc; rv[tid] = sv; rs[tid] = ssm;
    __syncthreads();
    for (int off = 128; off > 0; off >>= 1) {
        if (tid < off) {
            rc[tid] += rc[tid + off];
            rv[tid] += rv[tid + off];
            rs[tid] += rs[tid + off];
        }
        __syncthreads();
    }
    if (tid == 0) {
        double valid = rv[0];
        out[0] = (float)(rs[0] / (valid - (double)B_));  // m1.sum() = valid - B
        out[1] = (float)(rc[0] / valid);
    }
}

extern "C" void kernel_launch(void* const* d_in, const int* in_sizes, int n_in,
                              void* d_out, int out_size, void* d_ws, size_t ws_size,
                              hipStream_t stream) {
    const float* z    = (const float*)d_in[0];
    const float* cb   = (const float*)d_in[1];
    const float* mask = (const float*)d_in[2];
    float* out = (float*)d_out;
    char* ws = (char*)d_ws;

    float*              ee          = (float*)(ws + 64);
    unsigned long long* packed      = (unsigned long long*)(ws + 4224);
    int*                idxv        = (int*)(ws + 528512);
    int*                selpos      = (int*)(ws + 790656);
    int*                nst         = (int*)(ws + 1052800);
    float*              commit_part = (float*)(ws + 1053888);
    float*              valid_part  = (float*)(ws + 1054912);
    float*              smooth_part = (float*)(ws + 1055936);

    float* zqo   = out + 2;
    float* nzq   = zqo + (size_t)BT_ * C_;
    float* nmask = nzq + (size_t)BT_ * C_;
    float* sel   = nmask + BT_;

    k_init  <<<260,           256, 0, stream>>>(cb, ee, packed);
    k_assign<<<QBLK * KSPLIT, 256, 0, stream>>>(z, cb, ee, packed);
    k_epi   <<<256,           256, 0, stream>>>(z, cb, mask, packed, zqo, idxv,
                                                commit_part, valid_part,
                                                smooth_part);
    k_scan  <<<B_,            256, 0, stream>>>(idxv, mask, zqo, selpos, nst,
                                                smooth_part);
    k_gsel  <<<4096,          256, 0, stream>>>(zqo, idxv, selpos, nst,
                                                nzq, nmask, sel);
    k_final <<<1,             256, 0, stream>>>(commit_part, valid_part,
                                                smooth_part, out);
}

// Round 6
// 187.401 us; speedup vs baseline: 1.5163x; 1.3081x over previous
//
#include <hip/hip_runtime.h>
#include <math.h>

typedef __attribute__((ext_vector_type(8))) short short8;
typedef __attribute__((ext_vector_type(4))) float f32x4;

#define B_  16
#define T_  4096
#define C_  64
#define KE_ 1023
#define BT_ (B_ * T_)
#define WINDOW 1.5e-3f   // 2*delta guard band for bf16-split MFMA distances

// ---------------- ws layout (bytes) ----------------
// [0,       64)      int   flagcnt
// [64,      4160)    float ee[1024]        (|e_k|^2, ee[1023]=+inf pad)
// [4224,    135296)  u16   Eh[1024*64]     (bf16 hi of codebook[1:])
// [135296,  266368)  u16   El[1024*64]     (bf16 lo residual)
// [266368,  528512)  int   kbest[BT]
// [528512,  790656)  int   selpos[BT]
// [790656,  790720)  int   nst[B]
// [791680,  792704)  float commit_part[256]
// [792704,  793728)  float valid_part[256]
// [793728,  794816)  float smooth_part[272]
// [794816,  1056960) int   flaglist[BT]

__device__ __forceinline__ unsigned short f2bf(float x) {
    unsigned int u = __float_as_uint(x);
    unsigned int r = (u + 0x7FFFu + ((u >> 16) & 1u)) >> 16;   // RNE
    return (unsigned short)r;
}
__device__ __forceinline__ float bf2f(unsigned short h) {
    return __uint_as_float(((unsigned int)h) << 16);
}

// ---- prep: ee, bf16 hi/lo codebook, flagcnt=0 ----
__global__ __launch_bounds__(256) void k_prep(const float* __restrict__ cb,
                                              float* __restrict__ ee,
                                              unsigned short* __restrict__ Eh,
                                              unsigned short* __restrict__ El,
                                              int* __restrict__ flagcnt) {
    const int k = blockIdx.x * 256 + threadIdx.x;   // 0..1023
    if (k == 0) *flagcnt = 0;
    unsigned int* EhU = (unsigned int*)Eh;
    unsigned int* ElU = (unsigned int*)El;
    if (k < KE_) {
        const float* r = cb + (size_t)(k + 1) * C_;
        float s = 0.f;
        #pragma unroll
        for (int c = 0; c < C_; c += 2) {
            const float x0 = r[c], x1 = r[c + 1];
            s = fmaf(x0, x0, s);
            s = fmaf(x1, x1, s);
            const unsigned short h0 = f2bf(x0), h1 = f2bf(x1);
            const unsigned short l0 = f2bf(x0 - bf2f(h0));
            const unsigned short l1 = f2bf(x1 - bf2f(h1));
            EhU[k * 32 + c / 2] = (unsigned int)h0 | ((unsigned int)h1 << 16);
            ElU[k * 32 + c / 2] = (unsigned int)l0 | ((unsigned int)l1 << 16);
        }
        ee[k] = s;
    } else {        // k == 1023 pad: zero rows, inf distance
        #pragma unroll
        for (int c = 0; c < 32; ++c) { EhU[k * 32 + c] = 0u; ElU[k * 32 + c] = 0u; }
        ee[k] = INFINITY;
    }
}

// ---- hot kernel: bf16 hi/lo split MFMA + top-2 guard ----
// 512 blocks x 4 waves; block covers 128 queries x ALL 1024 codes.
// A-frag (m120): A[m=lane&15][k=quad*8+j]; B-frag mirror: B[k][n=lane&15];
// C/D (m89): col=lane&15, row=quad*4+reg. D = Zn * E^T.
// LDS code tiles: 128 codes, row stride 72 shorts (144B) -> 2-way-only
// bank aliasing on ds_read_b128 (free, m136).
__global__ __launch_bounds__(256, 4) void k_assign(
    const float* __restrict__ z, const unsigned short* __restrict__ Eh,
    const unsigned short* __restrict__ El, const float* __restrict__ ee,
    int* __restrict__ kbest, int* __restrict__ flaglist,
    int* __restrict__ flagcnt) {

    __shared__ __align__(16) unsigned short s_eh[128 * 72];
    __shared__ __align__(16) unsigned short s_el[128 * 72];
    __shared__ float s_ee[128];

    const int tid  = threadIdx.x;
    const int wave = tid >> 6;
    const int lane = tid & 63;
    const int col  = lane & 15;
    const int quad = lane >> 4;
    const int Q0   = blockIdx.x * 128 + wave * 32;

    // ---- A-frags: load z, normalize, bf16 hi/lo split, all in-register ----
    short8 ah[2][2], al[2][2];
    #pragma unroll
    for (int g = 0; g < 2; ++g) {
        const float4* zp = (const float4*)(z + (size_t)(Q0 + g * 16 + col) * C_);
        const float4 f0 = zp[quad * 2];
        const float4 f1 = zp[quad * 2 + 1];
        const float4 f2 = zp[8 + quad * 2];
        const float4 f3 = zp[8 + quad * 2 + 1];
        float xs[16] = {f0.x, f0.y, f0.z, f0.w, f1.x, f1.y, f1.z, f1.w,
                        f2.x, f2.y, f2.z, f2.w, f3.x, f3.y, f3.z, f3.w};
        float ss = 0.f;
        #pragma unroll
        for (int i = 0; i < 16; ++i) ss = fmaf(xs[i], xs[i], ss);
        ss += __shfl_xor(ss, 16);       // combine the 4 quads sharing this row
        ss += __shfl_xor(ss, 32);
        const float inv = 1.f / fmaxf(sqrtf(ss), 1e-12f);
        short8 h0, h1, l0, l1;
        #pragma unroll
        for (int i = 0; i < 8; ++i) {
            const float x = xs[i] * inv;
            const unsigned short hx = f2bf(x);
            h0[i] = (short)hx;
            l0[i] = (short)f2bf(x - bf2f(hx));
            const float y = xs[8 + i] * inv;
            const unsigned short hy = f2bf(y);
            h1[i] = (short)hy;
            l1[i] = (short)f2bf(y - bf2f(hy));
        }
        ah[g][0] = h0; ah[g][1] = h1;
        al[g][0] = l0; al[g][1] = l1;
    }

    float bestv[2][4], secv[2][4];
    int   bkk[2][4];
    #pragma unroll
    for (int g = 0; g < 2; ++g)
        #pragma unroll
        for (int r = 0; r < 4; ++r) {
            bestv[g][r] = INFINITY; secv[g][r] = INFINITY; bkk[g][r] = 0;
        }

    for (int t = 0; t < 8; ++t) {
        __syncthreads();               // previous tile fully consumed
        #pragma unroll
        for (int j = 0; j < 4; ++j) {  // stage 128 rows x 64 shorts, both mats
            const int p   = j * 256 + tid;   // 0..1023 (16B pieces)
            const int row = p >> 3;
            const int pc  = p & 7;
            *(uint4*)(&s_eh[row * 72 + pc * 8]) =
                *(const uint4*)(&Eh[(size_t)(t * 128 + row) * 64 + pc * 8]);
            *(uint4*)(&s_el[row * 72 + pc * 8]) =
                *(const uint4*)(&El[(size_t)(t * 128 + row) * 64 + pc * 8]);
        }
        if (tid < 128) s_ee[tid] = ee[t * 128 + tid];
        __syncthreads();

        #pragma unroll 2
        for (int s = 0; s < 8; ++s) {
            const int rbase = (s * 16 + col) * 72 + quad * 8;
            const short8 bh0 = *(const short8*)(&s_eh[rbase]);
            const short8 bh1 = *(const short8*)(&s_eh[rbase + 32]);
            const short8 bl0 = *(const short8*)(&s_el[rbase]);
            const short8 bl1 = *(const short8*)(&s_el[rbase + 32]);
            const float  eev = s_ee[s * 16 + col];

            f32x4 p0 = {0.f, 0.f, 0.f, 0.f}, q0 = {0.f, 0.f, 0.f, 0.f};
            f32x4 p1 = {0.f, 0.f, 0.f, 0.f}, q1 = {0.f, 0.f, 0.f, 0.f};
            // hi*hi
            p0 = __builtin_amdgcn_mfma_f32_16x16x32_bf16(ah[0][0], bh0, p0, 0, 0, 0);
            p1 = __builtin_amdgcn_mfma_f32_16x16x32_bf16(ah[1][0], bh0, p1, 0, 0, 0);
            q0 = __builtin_amdgcn_mfma_f32_16x16x32_bf16(ah[0][1], bh1, q0, 0, 0, 0);
            q1 = __builtin_amdgcn_mfma_f32_16x16x32_bf16(ah[1][1], bh1, q1, 0, 0, 0);
            // hi*lo
            p0 = __builtin_amdgcn_mfma_f32_16x16x32_bf16(ah[0][0], bl0, p0, 0, 0, 0);
            p1 = __builtin_amdgcn_mfma_f32_16x16x32_bf16(ah[1][0], bl0, p1, 0, 0, 0);
            q0 = __builtin_amdgcn_mfma_f32_16x16x32_bf16(ah[0][1], bl1, q0, 0, 0, 0);
            q1 = __builtin_amdgcn_mfma_f32_16x16x32_bf16(ah[1][1], bl1, q1, 0, 0, 0);
            // lo*hi
            p0 = __builtin_amdgcn_mfma_f32_16x16x32_bf16(al[0][0], bh0, p0, 0, 0, 0);
            p1 = __builtin_amdgcn_mfma_f32_16x16x32_bf16(al[1][0], bh0, p1, 0, 0, 0);
            q0 = __builtin_amdgcn_mfma_f32_16x16x32_bf16(al[0][1], bh1, q0, 0, 0, 0);
            q1 = __builtin_amdgcn_mfma_f32_16x16x32_bf16(al[1][1], bh1, q1, 0, 0, 0);

            const int kc = t * 128 + s * 16 + col;
            #pragma unroll
            for (int r = 0; r < 4; ++r) {
                {
                    const float v = fmaf(-2.f, p0[r] + q0[r], eev);
                    const bool lt = v < bestv[0][r];
                    secv[0][r]  = lt ? bestv[0][r] : fminf(secv[0][r], v);
                    bkk[0][r]   = lt ? kc : bkk[0][r];
                    bestv[0][r] = lt ? v : bestv[0][r];
                }
                {
                    const float v = fmaf(-2.f, p1[r] + q1[r], eev);
                    const bool lt = v < bestv[1][r];
                    secv[1][r]  = lt ? bestv[1][r] : fminf(secv[1][r], v);
                    bkk[1][r]   = lt ? kc : bkk[1][r];
                    bestv[1][r] = lt ? v : bestv[1][r];
                }
            }
        }
    }

    // ---- cross-lane top-2 merge within each 16-lane column group ----
    #pragma unroll
    for (int g = 0; g < 2; ++g) {
        #pragma unroll
        for (int r = 0; r < 4; ++r) {
            float b  = bestv[g][r], sc = secv[g][r];
            int   k  = bkk[g][r];
            #pragma unroll
            for (int off = 1; off < 16; off <<= 1) {
                const float ob = __shfl_xor(b, off);
                const int   ok = __shfl_xor(k, off);
                const float os = __shfl_xor(sc, off);
                const bool take = (ob < b) || (ob == b && ok < k);
                const float lose = take ? b : ob;
                sc = fminf(fminf(sc, os), lose);
                b  = take ? ob : b;
                k  = take ? ok : k;
            }
            if (col == 0) {
                const int q = Q0 + g * 16 + quad * 4 + r;
                kbest[q] = k;
                if (!(sc - b > WINDOW)) {              // ambiguous -> exact path
                    const int pos = atomicAdd(flagcnt, 1);
                    flaglist[pos] = q;
                }
            }
        }
    }
}

// ---- exact fp32 rescan for flagged (near-tie) queries: 1 wave/query ----
__global__ __launch_bounds__(256) void k_fix(const float* __restrict__ z,
                                             const float* __restrict__ cb,
                                             const float* __restrict__ ee,
                                             const int* __restrict__ flagcnt,
                                             const int* __restrict__ flaglist,
                                             int* __restrict__ kbest) {
    const int lane   = threadIdx.x & 63;
    const int waveId = (blockIdx.x * 256 + threadIdx.x) >> 6;
    const int n = *flagcnt;
    for (int i = waveId; i < n; i += 256) {
        const int q = flaglist[i];
        const float4* zp = (const float4*)(z + (size_t)q * C_);
        float4 zn[16];
        float ss = 0.f;
        #pragma unroll
        for (int c4 = 0; c4 < 16; ++c4) {
            const float4 v = zp[c4];
            zn[c4] = v;
            ss = fmaf(v.x, v.x, ss); ss = fmaf(v.y, v.y, ss);
            ss = fmaf(v.z, v.z, ss); ss = fmaf(v.w, v.w, ss);
        }
        const float nrm = fmaxf(sqrtf(ss), 1e-12f);
        #pragma unroll
        for (int c4 = 0; c4 < 16; ++c4) {
            zn[c4].x /= nrm; zn[c4].y /= nrm; zn[c4].z /= nrm; zn[c4].w /= nrm;
        }
        float bv = INFINITY;
        int   bk = 0;
        for (int j = 0; j < 16; ++j) {
            const int k = lane + j * 64;                 // ascending per lane
            const int crow = (k + 1 <= KE_) ? (k + 1) : KE_;
            const float4* er = (const float4*)(cb + (size_t)crow * C_);
            float d = 0.f;
            #pragma unroll
            for (int c4 = 0; c4 < 16; ++c4) {            // in-order fp32 chain
                const float4 e4 = er[c4];
                d = fmaf(zn[c4].x, e4.x, d); d = fmaf(zn[c4].y, e4.y, d);
                d = fmaf(zn[c4].z, e4.z, d); d = fmaf(zn[c4].w, e4.w, d);
            }
            const float v = fmaf(-2.f, d, ee[k]);        // inf at pad
            if (v < bv) { bv = v; bk = k; }
        }
        #pragma unroll
        for (int off = 32; off > 0; off >>= 1) {
            const float ov = __shfl_down(bv, off);
            const int   ok = __shfl_down(bk, off);
            if (ov < bv || (ov == bv && ok < bk)) { bv = ov; bk = ok; }
        }
        if (lane == 0) kbest[q] = bk;
    }
}

// ---- epilogue: z_q, commit/valid partials + in-block smoothness ----
__global__ __launch_bounds__(256) void k_epi(
    const float* __restrict__ z, const float* __restrict__ cb,
    const float* __restrict__ mask, const int* __restrict__ kbest,
    float* __restrict__ zqo,
    float* __restrict__ commit_part, float* __restrict__ valid_part,
    float* __restrict__ smooth_part) {

    __shared__ float4 s4[256];
    __shared__ float s_red[12];
    const int tid  = threadIdx.x;
    const int lane = tid & 63;
    const int wave = tid >> 6;
    const int q    = blockIdx.x * 256 + tid;

    const int bi = kbest[q];
    const float m     = mask[q];
    const float mnext = (tid < 255) ? mask[q + 1] : 0.f;   // pair (q, q+1)

    const float4* zp = (const float4*)(z + (size_t)q * C_);
    const float4* er = (const float4*)(cb + (size_t)(bi + 1) * C_);
    float4* zo = (float4*)(zqo + (size_t)q * C_);

    float4 zr[16];
    float ss = 0.f;
    #pragma unroll
    for (int i = 0; i < 16; ++i) {
        float4 v = zp[i];
        zr[i] = v;
        ss = fmaf(v.x, v.x, ss); ss = fmaf(v.y, v.y, ss);
        ss = fmaf(v.z, v.z, ss); ss = fmaf(v.w, v.w, ss);
    }
    const float nrm = fmaxf(sqrtf(ss), 1e-12f);

    float commit = 0.f, sm = 0.f;
    for (int c4 = 0; c4 < 16; ++c4) {
        const float z0 = zr[c4].x / nrm, z1 = zr[c4].y / nrm;
        const float z2 = zr[c4].z / nrm, z3 = zr[c4].w / nrm;
        const float4 e4 = er[c4];
        const float q0 = e4.x * m, q1 = e4.y * m, q2 = e4.z * m, q3 = e4.w * m;
        float4 o;
        o.x = (z0 + q0) - z0;              // straight-through forward value
        o.y = (z1 + q1) - z1;
        o.z = (z2 + q2) - z2;
        o.w = (z3 + q3) - z3;
        zo[c4] = o;
        const float d0 = z0 - q0, d1 = z1 - q1, d2 = z2 - q2, d3 = z3 - q3;
        commit = fmaf(d0, d0, commit); commit = fmaf(d1, d1, commit);
        commit = fmaf(d2, d2, commit); commit = fmaf(d3, d3, commit);
        s4[tid] = o;
        __syncthreads();
        if (tid < 255) {
            const float4 nb = s4[tid + 1];
            const float x0 = o.x - nb.x, x1 = o.y - nb.y;
            const float x2 = o.z - nb.z, x3 = o.w - nb.w;
            sm = fmaf(x0, x0, sm); sm = fmaf(x1, x1, sm);
            sm = fmaf(x2, x2, sm); sm = fmaf(x3, x3, sm);
        }
        __syncthreads();
    }
    commit *= m;
    sm     *= mnext;
    float vc = m;
    #pragma unroll
    for (int off = 32; off > 0; off >>= 1) {
        commit += __shfl_down(commit, off);
        vc     += __shfl_down(vc, off);
        sm     += __shfl_down(sm, off);
    }
    if (lane == 0) { s_red[wave] = commit; s_red[4 + wave] = vc; s_red[8 + wave] = sm; }
    __syncthreads();
    if (tid == 0) {
        commit_part[blockIdx.x] = s_red[0] + s_red[1] + s_red[2] + s_red[3];
        valid_part[blockIdx.x]  = s_red[4] + s_red[5] + s_red[6] + s_red[7];
        smooth_part[blockIdx.x] = s_red[8] + s_red[9] + s_red[10] + s_red[11];
    }
}

// ---- per-batch start compaction + boundary smoothness pairs ----
__global__ __launch_bounds__(256) void k_scan(const int* __restrict__ kbest,
                                              const float* __restrict__ mask,
                                              const float* __restrict__ zqo,
                                              int* __restrict__ selpos,
                                              int* __restrict__ nst,
                                              float* __restrict__ smooth_part) {
    __shared__ int cnt[256];
    __shared__ float sred[4];
    const int b = blockIdx.x;
    const int tid = threadIdx.x;
    const int base = b * T_;
    const int t0 = tid * 16;

    int flags = 0, c = 0;
    int prev = (tid == 0) ? -1 : kbest[base + t0 - 1];
    #pragma unroll
    for (int i = 0; i < 16; ++i) {
        const int t = t0 + i;
        const int cur = kbest[base + t];
        const int is = (t == 0) ? 1
                     : ((cur != prev && mask[base + t] > 0.f) ? 1 : 0);
        flags |= is << i;
        c += is;
        prev = cur;
    }
    cnt[tid] = c;
    __syncthreads();
    for (int off = 1; off < 256; off <<= 1) {
        int add = (tid >= off) ? cnt[tid - off] : 0;
        __syncthreads();
        cnt[tid] += add;
        __syncthreads();
    }
    int pos = cnt[tid] - c;   // exclusive prefix
    #pragma unroll
    for (int i = 0; i < 16; ++i) {
        if ((flags >> i) & 1) selpos[base + pos++] = t0 + i;
    }
    if (tid == 255) nst[b] = cnt[255];

    // boundary smoothness pairs: (q-1, q) at q = base + j*256, j=1..15
    float v = 0.f;
    for (int e = tid; e < 15 * 64; e += 256) {
        const int j = e >> 6, cc = e & 63;
        const int q = base + (j + 1) * 256;
        const float d = zqo[(size_t)(q - 1) * C_ + cc] - zqo[(size_t)q * C_ + cc];
        v = fmaf(d * mask[q], d, v);
    }
    #pragma unroll
    for (int off = 32; off > 0; off >>= 1) v += __shfl_down(v, off);
    if ((tid & 63) == 0) sred[tid >> 6] = v;
    __syncthreads();
    if (tid == 0) smooth_part[256 + b] = sred[0] + sred[1] + sred[2] + sred[3];
}

// ---- fused n_z_q gather + n_mask + selected_encodings ----
__global__ __launch_bounds__(256) void k_gsel(const float* __restrict__ zqo,
                                              const int* __restrict__ kbest,
                                              const int* __restrict__ selpos,
                                              const int* __restrict__ nst,
                                              float* __restrict__ nzq,
                                              float* __restrict__ nmask,
                                              float* __restrict__ sel) {
    const int gid = blockIdx.x * 256 + threadIdx.x;   // float4 index
    const int b   = gid >> 16;          // T*C/4 = 65536 float4 per batch
    const int rem = gid & 65535;
    const int j   = rem >> 4;
    const int c4  = rem & 15;
    const int n   = nst[b];
    float4 v = make_float4(0.f, 0.f, 0.f, 0.f);
    int p = 0;
    if (j < n) {
        p = selpos[b * T_ + j];
        v = ((const float4*)zqo)[((size_t)b * T_ + p) * 16 + c4];
    }
    ((float4*)nzq)[gid] = v;
    if (c4 == 0) {
        float nm = 0.f, s = 0.f;
        if (j < n) { nm = 1.f; s = (float)(kbest[b * T_ + p] + 1); }
        nmask[b * T_ + j] = nm;
        sel[b * T_ + j]   = s;
    }
}

// ---- final reduction of partials -> losses ----
__global__ __launch_bounds__(256) void k_final(const float* __restrict__ commit_part,
                                               const float* __restrict__ valid_part,
                                               const float* __restrict__ smooth_part,
                                               float* __restrict__ out) {
    __shared__ double rc[256];
    __shared__ double rv[256];
    __shared__ double rs[256];
    const int tid = threadIdx.x;
    double sc = (double)commit_part[tid];
    double sv = (double)valid_part[tid];
    double ssm = (double)smooth_part[tid];
    if (tid < 16) ssm += (double)smooth_part[256 + tid];
    rc[tid] = sc; rv[tid] = sv; rs[tid] = ssm;
    __syncthreads();
    for (int off = 128; off > 0; off >>= 1) {
        if (tid < off) {
            rc[tid] += rc[tid + off];
            rv[tid] += rv[tid + off];
            rs[tid] += rs[tid + off];
        }
        __syncthreads();
    }
    if (tid == 0) {
        double valid = rv[0];
        out[0] = (float)(rs[0] / (valid - (double)B_));  // m1.sum() = valid - B
        out[1] = (float)(rc[0] / valid);
    }
}

extern "C" void kernel_launch(void* const* d_in, const int* in_sizes, int n_in,
                              void* d_out, int out_size, void* d_ws, size_t ws_size,
                              hipStream_t stream) {
    const float* z    = (const float*)d_in[0];
    const float* cb   = (const float*)d_in[1];
    const float* mask = (const float*)d_in[2];
    float* out = (float*)d_out;
    char* ws = (char*)d_ws;

    int*            flagcnt     = (int*)(ws + 0);
    float*          ee          = (float*)(ws + 64);
    unsigned short* Eh          = (unsigned short*)(ws + 4224);
    unsigned short* El          = (unsigned short*)(ws + 135296);
    int*            kbest       = (int*)(ws + 266368);
    int*            selpos      = (int*)(ws + 528512);
    int*            nst         = (int*)(ws + 790656);
    float*          commit_part = (float*)(ws + 791680);
    float*          valid_part  = (float*)(ws + 792704);
    float*          smooth_part = (float*)(ws + 793728);
    int*            flaglist    = (int*)(ws + 794816);

    float* zqo   = out + 2;
    float* nzq   = zqo + (size_t)BT_ * C_;
    float* nmask = nzq + (size_t)BT_ * C_;
    float* sel   = nmask + BT_;

    k_prep  <<<4,    256, 0, stream>>>(cb, ee, Eh, El, flagcnt);
    k_assign<<<512,  256, 0, stream>>>(z, Eh, El, ee, kbest, flaglist, flagcnt);
    k_fix   <<<64,   256, 0, stream>>>(z, cb, ee, flagcnt, flaglist, kbest);
    k_epi   <<<256,  256, 0, stream>>>(z, cb, mask, kbest, zqo,
                                       commit_part, valid_part, smooth_part);
    k_scan  <<<B_,   256, 0, stream>>>(kbest, mask, zqo, selpos, nst, smooth_part);
    k_gsel  <<<4096, 256, 0, stream>>>(zqo, kbest, selpos, nst, nzq, nmask, sel);
    k_final <<<1,    256, 0, stream>>>(commit_part, valid_part, smooth_part, out);
}

// Round 7
// 157.379 us; speedup vs baseline: 1.8056x; 1.1908x over previous
//
#include <hip/hip_runtime.h>
#include <math.h>

typedef __attribute__((ext_vector_type(8))) short short8;
typedef __attribute__((ext_vector_type(4))) float f32x4;

#define B_  16
#define T_  4096
#define C_  64
#define KE_ 1023
#define BT_ (B_ * T_)
#define WINDOW 1e-3f   // guard band >= 3x provable bf16-split distance error

// ---------------- ws layout (bytes) ----------------
// [0,       64)      int   flagcnt
// [64,      4160)    float ee[1024]        (|e_k|^2, ee[1023]=+inf pad)
// [4224,    135296)  u16   Eh[1024*64]     (bf16 hi of codebook[1:])
// [135296,  266368)  u16   El[1024*64]     (bf16 lo residual)
// [266368,  528512)  int   kbest[BT]
// [528512,  790656)  int   selpos[BT]
// [790656,  790720)  int   nst[B]
// [791680,  792704)  float commit_part[256]
// [792704,  793728)  float valid_part[256]
// [793728,  794816)  float smooth_part[272]
// [794816,  1056960) int   flaglist[BT]

__device__ __forceinline__ unsigned short f2bf(float x) {
    unsigned int u = __float_as_uint(x);
    unsigned int r = (u + 0x7FFFu + ((u >> 16) & 1u)) >> 16;   // RNE
    return (unsigned short)r;
}
__device__ __forceinline__ float bf2f(unsigned short h) {
    return __uint_as_float(((unsigned int)h) << 16);
}

// ---- prep: ee, bf16 hi/lo codebook, flagcnt=0 ----
__global__ __launch_bounds__(256) void k_prep(const float* __restrict__ cb,
                                              float* __restrict__ ee,
                                              unsigned short* __restrict__ Eh,
                                              unsigned short* __restrict__ El,
                                              int* __restrict__ flagcnt) {
    const int k = blockIdx.x * 256 + threadIdx.x;   // 0..1023
    if (k == 0) *flagcnt = 0;
    unsigned int* EhU = (unsigned int*)Eh;
    unsigned int* ElU = (unsigned int*)El;
    if (k < KE_) {
        const float* r = cb + (size_t)(k + 1) * C_;
        float s = 0.f;
        #pragma unroll
        for (int c = 0; c < C_; c += 2) {
            const float x0 = r[c], x1 = r[c + 1];
            s = fmaf(x0, x0, s);
            s = fmaf(x1, x1, s);
            const unsigned short h0 = f2bf(x0), h1 = f2bf(x1);
            const unsigned short l0 = f2bf(x0 - bf2f(h0));
            const unsigned short l1 = f2bf(x1 - bf2f(h1));
            EhU[k * 32 + c / 2] = (unsigned int)h0 | ((unsigned int)h1 << 16);
            ElU[k * 32 + c / 2] = (unsigned int)l0 | ((unsigned int)l1 << 16);
        }
        ee[k] = s;
    } else {        // k == 1023 pad: zero rows, inf distance
        #pragma unroll
        for (int c = 0; c < 32; ++c) { EhU[k * 32 + c] = 0u; ElU[k * 32 + c] = 0u; }
        ee[k] = INFINITY;
    }
}

// ---- hot kernel: bf16 hi/lo split MFMA + top-2 guard (verified R6) ----
__global__ __launch_bounds__(256, 4) void k_assign(
    const float* __restrict__ z, const unsigned short* __restrict__ Eh,
    const unsigned short* __restrict__ El, const float* __restrict__ ee,
    int* __restrict__ kbest, int* __restrict__ flaglist,
    int* __restrict__ flagcnt) {

    __shared__ __align__(16) unsigned short s_eh[128 * 72];
    __shared__ __align__(16) unsigned short s_el[128 * 72];
    __shared__ float s_ee[128];

    const int tid  = threadIdx.x;
    const int wave = tid >> 6;
    const int lane = tid & 63;
    const int col  = lane & 15;
    const int quad = lane >> 4;
    const int Q0   = blockIdx.x * 128 + wave * 32;

    short8 ah[2][2], al[2][2];
    #pragma unroll
    for (int g = 0; g < 2; ++g) {
        const float4* zp = (const float4*)(z + (size_t)(Q0 + g * 16 + col) * C_);
        const float4 f0 = zp[quad * 2];
        const float4 f1 = zp[quad * 2 + 1];
        const float4 f2 = zp[8 + quad * 2];
        const float4 f3 = zp[8 + quad * 2 + 1];
        float xs[16] = {f0.x, f0.y, f0.z, f0.w, f1.x, f1.y, f1.z, f1.w,
                        f2.x, f2.y, f2.z, f2.w, f3.x, f3.y, f3.z, f3.w};
        float ss = 0.f;
        #pragma unroll
        for (int i = 0; i < 16; ++i) ss = fmaf(xs[i], xs[i], ss);
        ss += __shfl_xor(ss, 16);
        ss += __shfl_xor(ss, 32);
        const float inv = 1.f / fmaxf(sqrtf(ss), 1e-12f);
        short8 h0, h1, l0, l1;
        #pragma unroll
        for (int i = 0; i < 8; ++i) {
            const float x = xs[i] * inv;
            const unsigned short hx = f2bf(x);
            h0[i] = (short)hx;
            l0[i] = (short)f2bf(x - bf2f(hx));
            const float y = xs[8 + i] * inv;
            const unsigned short hy = f2bf(y);
            h1[i] = (short)hy;
            l1[i] = (short)f2bf(y - bf2f(hy));
        }
        ah[g][0] = h0; ah[g][1] = h1;
        al[g][0] = l0; al[g][1] = l1;
    }

    float bestv[2][4], secv[2][4];
    int   bkk[2][4];
    #pragma unroll
    for (int g = 0; g < 2; ++g)
        #pragma unroll
        for (int r = 0; r < 4; ++r) {
            bestv[g][r] = INFINITY; secv[g][r] = INFINITY; bkk[g][r] = 0;
        }

    for (int t = 0; t < 8; ++t) {
        __syncthreads();
        #pragma unroll
        for (int j = 0; j < 4; ++j) {
            const int p   = j * 256 + tid;
            const int row = p >> 3;
            const int pc  = p & 7;
            *(uint4*)(&s_eh[row * 72 + pc * 8]) =
                *(const uint4*)(&Eh[(size_t)(t * 128 + row) * 64 + pc * 8]);
            *(uint4*)(&s_el[row * 72 + pc * 8]) =
                *(const uint4*)(&El[(size_t)(t * 128 + row) * 64 + pc * 8]);
        }
        if (tid < 128) s_ee[tid] = ee[t * 128 + tid];
        __syncthreads();

        #pragma unroll 2
        for (int s = 0; s < 8; ++s) {
            const int rbase = (s * 16 + col) * 72 + quad * 8;
            const short8 bh0 = *(const short8*)(&s_eh[rbase]);
            const short8 bh1 = *(const short8*)(&s_eh[rbase + 32]);
            const short8 bl0 = *(const short8*)(&s_el[rbase]);
            const short8 bl1 = *(const short8*)(&s_el[rbase + 32]);
            const float  eev = s_ee[s * 16 + col];

            f32x4 p0 = {0.f, 0.f, 0.f, 0.f}, q0 = {0.f, 0.f, 0.f, 0.f};
            f32x4 p1 = {0.f, 0.f, 0.f, 0.f}, q1 = {0.f, 0.f, 0.f, 0.f};
            p0 = __builtin_amdgcn_mfma_f32_16x16x32_bf16(ah[0][0], bh0, p0, 0, 0, 0);
            p1 = __builtin_amdgcn_mfma_f32_16x16x32_bf16(ah[1][0], bh0, p1, 0, 0, 0);
            q0 = __builtin_amdgcn_mfma_f32_16x16x32_bf16(ah[0][1], bh1, q0, 0, 0, 0);
            q1 = __builtin_amdgcn_mfma_f32_16x16x32_bf16(ah[1][1], bh1, q1, 0, 0, 0);
            p0 = __builtin_amdgcn_mfma_f32_16x16x32_bf16(ah[0][0], bl0, p0, 0, 0, 0);
            p1 = __builtin_amdgcn_mfma_f32_16x16x32_bf16(ah[1][0], bl0, p1, 0, 0, 0);
            q0 = __builtin_amdgcn_mfma_f32_16x16x32_bf16(ah[0][1], bl1, q0, 0, 0, 0);
            q1 = __builtin_amdgcn_mfma_f32_16x16x32_bf16(ah[1][1], bl1, q1, 0, 0, 0);
            p0 = __builtin_amdgcn_mfma_f32_16x16x32_bf16(al[0][0], bh0, p0, 0, 0, 0);
            p1 = __builtin_amdgcn_mfma_f32_16x16x32_bf16(al[1][0], bh0, p1, 0, 0, 0);
            q0 = __builtin_amdgcn_mfma_f32_16x16x32_bf16(al[0][1], bh1, q0, 0, 0, 0);
            q1 = __builtin_amdgcn_mfma_f32_16x16x32_bf16(al[1][1], bh1, q1, 0, 0, 0);

            const int kc = t * 128 + s * 16 + col;
            #pragma unroll
            for (int r = 0; r < 4; ++r) {
                {
                    const float v = fmaf(-2.f, p0[r] + q0[r], eev);
                    const bool lt = v < bestv[0][r];
                    secv[0][r]  = lt ? bestv[0][r] : fminf(secv[0][r], v);
                    bkk[0][r]   = lt ? kc : bkk[0][r];
                    bestv[0][r] = lt ? v : bestv[0][r];
                }
                {
                    const float v = fmaf(-2.f, p1[r] + q1[r], eev);
                    const bool lt = v < bestv[1][r];
                    secv[1][r]  = lt ? bestv[1][r] : fminf(secv[1][r], v);
                    bkk[1][r]   = lt ? kc : bkk[1][r];
                    bestv[1][r] = lt ? v : bestv[1][r];
                }
            }
        }
    }

    #pragma unroll
    for (int g = 0; g < 2; ++g) {
        #pragma unroll
        for (int r = 0; r < 4; ++r) {
            float b  = bestv[g][r], sc = secv[g][r];
            int   k  = bkk[g][r];
            #pragma unroll
            for (int off = 1; off < 16; off <<= 1) {
                const float ob = __shfl_xor(b, off);
                const int   ok = __shfl_xor(k, off);
                const float os = __shfl_xor(sc, off);
                const bool take = (ob < b) || (ob == b && ok < k);
                const float lose = take ? b : ob;
                sc = fminf(fminf(sc, os), lose);
                b  = take ? ob : b;
                k  = take ? ok : k;
            }
            if (col == 0) {
                const int q = Q0 + g * 16 + quad * 4 + r;
                kbest[q] = k;
                if (!(sc - b > WINDOW)) {              // ambiguous -> exact path
                    const int pos = atomicAdd(flagcnt, 1);
                    flaglist[pos] = q;
                }
            }
        }
    }
}

// ---- exact fp32 rescan, BLOCK per flagged query (throughput-bound) ----
// z row staged in LDS (broadcast reads); thread t scans codes 4t..4t+3 with
// 4 independent in-order fp32 chains (identical arithmetic to verified R6);
// block covers all 256KB of cb (L2-hot, coalesced across threads).
__global__ __launch_bounds__(256) void k_fix(const float* __restrict__ z,
                                             const float* __restrict__ cb,
                                             const float* __restrict__ ee,
                                             const int* __restrict__ flagcnt,
                                             const int* __restrict__ flaglist,
                                             int* __restrict__ kbest) {
    __shared__ float s_z[64];
    __shared__ float s_bv[4];
    __shared__ int   s_bk[4];
    const int tid  = threadIdx.x;
    const int lane = tid & 63;
    const int wave = tid >> 6;
    const int n = *flagcnt;

    for (int i = blockIdx.x; i < n; i += 1024) {
        const int q = flaglist[i];
        __syncthreads();               // s_z reuse guard across iterations
        if (tid < 16) ((float4*)s_z)[tid] = ((const float4*)(z + (size_t)q * C_))[tid];
        __syncthreads();

        float4 zn[16];
        float ss = 0.f;
        #pragma unroll
        for (int c4 = 0; c4 < 16; ++c4) {
            const float4 v = ((const float4*)s_z)[c4];
            zn[c4] = v;
            ss = fmaf(v.x, v.x, ss); ss = fmaf(v.y, v.y, ss);
            ss = fmaf(v.z, v.z, ss); ss = fmaf(v.w, v.w, ss);
        }
        const float nrm = fmaxf(sqrtf(ss), 1e-12f);
        #pragma unroll
        for (int c4 = 0; c4 < 16; ++c4) {
            zn[c4].x /= nrm; zn[c4].y /= nrm; zn[c4].z /= nrm; zn[c4].w /= nrm;
        }

        const int k0 = tid * 4;        // codes k0..k0+3 (k0+3 <= 1023)
        const float4* e0 = (const float4*)(cb + (size_t)(k0 + 1) * C_);
        const float4* e1 = (const float4*)(cb + (size_t)(k0 + 2) * C_);
        const float4* e2 = (const float4*)(cb + (size_t)(k0 + 3) * C_);
        const float4* e3 = (const float4*)(cb + (size_t)((k0 + 4 <= KE_) ? (k0 + 4) : KE_) * C_);
        float d0 = 0.f, d1 = 0.f, d2 = 0.f, d3 = 0.f;
        #pragma unroll
        for (int c4 = 0; c4 < 16; ++c4) {   // in-order fp32 chains
            const float4 x = zn[c4];
            const float4 a = e0[c4], b = e1[c4], c = e2[c4], d = e3[c4];
            d0 = fmaf(x.x, a.x, d0); d0 = fmaf(x.y, a.y, d0);
            d0 = fmaf(x.z, a.z, d0); d0 = fmaf(x.w, a.w, d0);
            d1 = fmaf(x.x, b.x, d1); d1 = fmaf(x.y, b.y, d1);
            d1 = fmaf(x.z, b.z, d1); d1 = fmaf(x.w, b.w, d1);
            d2 = fmaf(x.x, c.x, d2); d2 = fmaf(x.y, c.y, d2);
            d2 = fmaf(x.z, c.z, d2); d2 = fmaf(x.w, c.w, d2);
            d3 = fmaf(x.x, d.x, d3); d3 = fmaf(x.y, d.y, d3);
            d3 = fmaf(x.z, d.z, d3); d3 = fmaf(x.w, d.w, d3);
        }
        float bv = INFINITY;
        int   bk = 0;
        float v;
        v = fmaf(-2.f, d0, ee[k0 + 0]); if (v < bv) { bv = v; bk = k0 + 0; }
        v = fmaf(-2.f, d1, ee[k0 + 1]); if (v < bv) { bv = v; bk = k0 + 1; }
        v = fmaf(-2.f, d2, ee[k0 + 2]); if (v < bv) { bv = v; bk = k0 + 2; }
        v = fmaf(-2.f, d3, ee[k0 + 3]); if (v < bv) { bv = v; bk = k0 + 3; }

        #pragma unroll
        for (int off = 32; off > 0; off >>= 1) {
            const float ov = __shfl_down(bv, off);
            const int   ok = __shfl_down(bk, off);
            if (ov < bv || (ov == bv && ok < bk)) { bv = ov; bk = ok; }
        }
        if (lane == 0) { s_bv[wave] = bv; s_bk[wave] = bk; }
        __syncthreads();
        if (tid == 0) {
            float fb = s_bv[0]; int fk = s_bk[0];
            #pragma unroll
            for (int w = 1; w < 4; ++w) {
                if (s_bv[w] < fb || (s_bv[w] == fb && s_bk[w] < fk)) {
                    fb = s_bv[w]; fk = s_bk[w];
                }
            }
            kbest[q] = fk;
        }
    }
}

// ---- epilogue: z_q, commit/valid partials + wave-local smoothness ----
// neighbor via shfl_down(o,1); lane-63 pairs (t%64==63) handled in k_scan.
__global__ __launch_bounds__(256) void k_epi(
    const float* __restrict__ z, const float* __restrict__ cb,
    const float* __restrict__ mask, const int* __restrict__ kbest,
    float* __restrict__ zqo,
    float* __restrict__ commit_part, float* __restrict__ valid_part,
    float* __restrict__ smooth_part) {

    __shared__ float s_red[12];
    const int tid  = threadIdx.x;
    const int lane = tid & 63;
    const int wave = tid >> 6;
    const int q    = blockIdx.x * 256 + tid;

    const int bi = kbest[q];
    const float m     = mask[q];
    const float mnext = (lane != 63) ? mask[q + 1] : 0.f;

    const float4* zp = (const float4*)(z + (size_t)q * C_);
    const float4* er = (const float4*)(cb + (size_t)(bi + 1) * C_);
    float4* zo = (float4*)(zqo + (size_t)q * C_);

    float4 zr[16];
    float ss = 0.f;
    #pragma unroll
    for (int i = 0; i < 16; ++i) {
        float4 v = zp[i];
        zr[i] = v;
        ss = fmaf(v.x, v.x, ss); ss = fmaf(v.y, v.y, ss);
        ss = fmaf(v.z, v.z, ss); ss = fmaf(v.w, v.w, ss);
    }
    const float nrm = fmaxf(sqrtf(ss), 1e-12f);

    float commit = 0.f, sm = 0.f;
    #pragma unroll
    for (int c4 = 0; c4 < 16; ++c4) {
        const float z0 = zr[c4].x / nrm, z1 = zr[c4].y / nrm;
        const float z2 = zr[c4].z / nrm, z3 = zr[c4].w / nrm;
        const float4 e4 = er[c4];
        const float q0 = e4.x * m, q1 = e4.y * m, q2 = e4.z * m, q3 = e4.w * m;
        float4 o;
        o.x = (z0 + q0) - z0;              // straight-through forward value
        o.y = (z1 + q1) - z1;
        o.z = (z2 + q2) - z2;
        o.w = (z3 + q3) - z3;
        zo[c4] = o;
        const float d0 = z0 - q0, d1 = z1 - q1, d2 = z2 - q2, d3 = z3 - q3;
        commit = fmaf(d0, d0, commit); commit = fmaf(d1, d1, commit);
        commit = fmaf(d2, d2, commit); commit = fmaf(d3, d3, commit);
        // wave-local smoothness pair (q, q+1): neighbor regs via shfl
        const float n0 = __shfl_down(o.x, 1);
        const float n1 = __shfl_down(o.y, 1);
        const float n2 = __shfl_down(o.z, 1);
        const float n3 = __shfl_down(o.w, 1);
        const float x0 = o.x - n0, x1 = o.y - n1;
        const float x2 = o.z - n2, x3 = o.w - n3;
        sm = fmaf(x0, x0, sm); sm = fmaf(x1, x1, sm);
        sm = fmaf(x2, x2, sm); sm = fmaf(x3, x3, sm);
    }
    commit *= m;
    sm     *= mnext;
    float vc = m;
    #pragma unroll
    for (int off = 32; off > 0; off >>= 1) {
        commit += __shfl_down(commit, off);
        vc     += __shfl_down(vc, off);
        sm     += __shfl_down(sm, off);
    }
    if (lane == 0) { s_red[wave] = commit; s_red[4 + wave] = vc; s_red[8 + wave] = sm; }
    __syncthreads();
    if (tid == 0) {
        commit_part[blockIdx.x] = s_red[0] + s_red[1] + s_red[2] + s_red[3];
        valid_part[blockIdx.x]  = s_red[4] + s_red[5] + s_red[6] + s_red[7];
        smooth_part[blockIdx.x] = s_red[8] + s_red[9] + s_red[10] + s_red[11];
    }
}

// ---- per-batch start compaction + wave-boundary smoothness pairs ----
__global__ __launch_bounds__(256) void k_scan(const int* __restrict__ kbest,
                                              const float* __restrict__ mask,
                                              const float* __restrict__ zqo,
                                              int* __restrict__ selpos,
                                              int* __restrict__ nst,
                                              float* __restrict__ smooth_part) {
    __shared__ int cnt[256];
    __shared__ float sred[4];
    const int b = blockIdx.x;
    const int tid = threadIdx.x;
    const int base = b * T_;
    const int t0 = tid * 16;

    int flags = 0, c = 0;
    int prev = (tid == 0) ? -1 : kbest[base + t0 - 1];
    #pragma unroll
    for (int i = 0; i < 16; ++i) {
        const int t = t0 + i;
        const int cur = kbest[base + t];
        const int is = (t == 0) ? 1
                     : ((cur != prev && mask[base + t] > 0.f) ? 1 : 0);
        flags |= is << i;
        c += is;
        prev = cur;
    }
    cnt[tid] = c;
    __syncthreads();
    for (int off = 1; off < 256; off <<= 1) {
        int add = (tid >= off) ? cnt[tid - off] : 0;
        __syncthreads();
        cnt[tid] += add;
        __syncthreads();
    }
    int pos = cnt[tid] - c;   // exclusive prefix
    #pragma unroll
    for (int i = 0; i < 16; ++i) {
        if ((flags >> i) & 1) selpos[base + pos++] = t0 + i;
    }
    if (tid == 255) nst[b] = cnt[255];

    // boundary smoothness pairs: (t, t+1) at t = 63 + j*64, j=0..62
    float v = 0.f;
    for (int e = tid; e < 63 * 64; e += 256) {
        const int j = e >> 6, cc = e & 63;
        const int t = j * 64 + 63;
        const int qq = base + t;
        const float d = zqo[(size_t)qq * C_ + cc] - zqo[(size_t)(qq + 1) * C_ + cc];
        v = fmaf(d * mask[qq + 1], d, v);
    }
    #pragma unroll
    for (int off = 32; off > 0; off >>= 1) v += __shfl_down(v, off);
    if ((tid & 63) == 0) sred[tid >> 6] = v;
    __syncthreads();
    if (tid == 0) smooth_part[256 + b] = sred[0] + sred[1] + sred[2] + sred[3];
}

// ---- fused n_z_q gather + n_mask + selected_encodings ----
__global__ __launch_bounds__(256) void k_gsel(const float* __restrict__ zqo,
                                              const int* __restrict__ kbest,
                                              const int* __restrict__ selpos,
                                              const int* __restrict__ nst,
                                              float* __restrict__ nzq,
                                              float* __restrict__ nmask,
                                              float* __restrict__ sel) {
    const int gid = blockIdx.x * 256 + threadIdx.x;   // float4 index
    const int b   = gid >> 16;          // T*C/4 = 65536 float4 per batch
    const int rem = gid & 65535;
    const int j   = rem >> 4;
    const int c4  = rem & 15;
    const int n   = nst[b];
    float4 v = make_float4(0.f, 0.f, 0.f, 0.f);
    int p = 0;
    if (j < n) {
        p = selpos[b * T_ + j];
        v = ((const float4*)zqo)[((size_t)b * T_ + p) * 16 + c4];
    }
    ((float4*)nzq)[gid] = v;
    if (c4 == 0) {
        float nm = 0.f, s = 0.f;
        if (j < n) { nm = 1.f; s = (float)(kbest[b * T_ + p] + 1); }
        nmask[b * T_ + j] = nm;
        sel[b * T_ + j]   = s;
    }
}

// ---- final reduction of partials -> losses ----
__global__ __launch_bounds__(256) void k_final(const float* __restrict__ commit_part,
                                               const float* __restrict__ valid_part,
                                               const float* __restrict__ smooth_part,
                                               float* __restrict__ out) {
    __shared__ double rc[256];
    __shared__ double rv[256];
    __shared__ double rs[256];
    const int tid = threadIdx.x;
    double sc = (double)commit_part[tid];
    double sv = (double)valid_part[tid];
    double ssm = (double)smooth_part[tid];
    if (tid < 16) ssm += (double)smooth_part[256 + tid];
    rc[tid] = sc; rv[tid] = sv; rs[tid] = ssm;
    __syncthreads();
    for (int off = 128; off > 0; off >>= 1) {
        if (tid < off) {
            rc[tid] += rc[tid + off];
            rv[tid] += rv[tid + off];
            rs[tid] += rs[tid + off];
        }
        __syncthreads();
    }
    if (tid == 0) {
        double valid = rv[0];
        out[0] = (float)(rs[0] / (valid - (double)B_));  // m1.sum() = valid - B
        out[1] = (float)(rc[0] / valid);
    }
}

extern "C" void kernel_launch(void* const* d_in, const int* in_sizes, int n_in,
                              void* d_out, int out_size, void* d_ws, size_t ws_size,
                              hipStream_t stream) {
    const float* z    = (const float*)d_in[0];
    const float* cb   = (const float*)d_in[1];
    const float* mask = (const float*)d_in[2];
    float* out = (float*)d_out;
    char* ws = (char*)d_ws;

    int*            flagcnt     = (int*)(ws + 0);
    float*          ee          = (float*)(ws + 64);
    unsigned short* Eh          = (unsigned short*)(ws + 4224);
    unsigned short* El          = (unsigned short*)(ws + 135296);
    int*            kbest       = (int*)(ws + 266368);
    int*            selpos      = (int*)(ws + 528512);
    int*            nst         = (int*)(ws + 790656);
    float*          commit_part = (float*)(ws + 791680);
    float*          valid_part  = (float*)(ws + 792704);
    float*          smooth_part = (float*)(ws + 793728);
    int*            flaglist    = (int*)(ws + 794816);

    float* zqo   = out + 2;
    float* nzq   = zqo + (size_t)BT_ * C_;
    float* nmask = nzq + (size_t)BT_ * C_;
    float* sel   = nmask + BT_;

    k_prep  <<<4,    256, 0, stream>>>(cb, ee, Eh, El, flagcnt);
    k_assign<<<512,  256, 0, stream>>>(z, Eh, El, ee, kbest, flaglist, flagcnt);
    k_fix   <<<1024, 256, 0, stream>>>(z, cb, ee, flagcnt, flaglist, kbest);
    k_epi   <<<256,  256, 0, stream>>>(z, cb, mask, kbest, zqo,
                                       commit_part, valid_part, smooth_part);
    k_scan  <<<B_,   256, 0, stream>>>(kbest, mask, zqo, selpos, nst, smooth_part);
    k_gsel  <<<4096, 256, 0, stream>>>(zqo, kbest, selpos, nst, nzq, nmask, sel);
    k_final <<<1,    256, 0, stream>>>(commit_part, valid_part, smooth_part, out);
}